// Round 9
// baseline (283.854 us; speedup 1.0000x reference)
//
#include <hip/hip_runtime.h>
#include <hip/hip_fp16.h>
#include <cstdint>
#include <cstddef>

#define NEG_SLOPE 0.2f
#define LN_EPS 1e-5f

constexpr int BS = 256;

typedef _Float16 f16x8 __attribute__((ext_vector_type(8)));
typedef float f32x4 __attribute__((ext_vector_type(4)));

// ============================ linked-list CSR ============================
// head[]=-1 (memset 0xFF), deg[]=0 (memset 0). One coalesced int2 write per
// edge; random ops are two L2-resident 4B atomics (exch + histogram add).
// Also inits gctr and the 16-entry zero pad after sw (OOB-gather safety).
__global__ void k_link(const int* __restrict__ esrc, const int* __restrict__ edst,
                       int* __restrict__ head, int* __restrict__ deg,
                       int2* __restrict__ nxt2, int* __restrict__ gctr,
                       int2* __restrict__ sw, int e, int etot) {
    int i = blockIdx.x * BS + threadIdx.x;
    if (i == 0) *gctr = 0;
    if (i < 16) sw[etot + i] = make_int2(0, 0);
    if (i >= etot) return;
    int s, d;
    if (i < e) { s = esrc[i]; d = edst[i]; }
    else       { s = d = i - e; }          // self loop
    int old = atomicExch(&head[d], i);
    atomicAdd(&deg[d], 1);
    nxt2[i] = make_int2(old, s);           // {next ptr, src node}
}

// the ONLY chain walk: reserve the node's slot segment (order irrelevant),
// write per-slot {src byte-offset, node id}.
__global__ void k_slots(const int* __restrict__ head, const int2* __restrict__ nxt2,
                        const int* __restrict__ deg, int* __restrict__ gctr,
                        int2* __restrict__ offs2, int2* __restrict__ sn, int n) {
    int i = blockIdx.x * BS + threadIdx.x;
    if (i >= n) return;
    int d = deg[i];
    int pos = atomicAdd(gctr, d);
    offs2[i] = make_int2(pos, d);
    int j = head[i];
    while (j >= 0) {
        int2 p = nxt2[j];
        sn[pos++] = make_int2(p.y << 8, i);   // src*256 = fp16 row byte off
        j = p.x;
    }
}

// per-layer, slot-parallel: w = exp(leaky(as[src] + ad[nid])). Coalesced
// sn read / sw write; the random as_ gather is hidden by 650k threads.
__global__ void k_w(const int2* __restrict__ sn, const float* __restrict__ as_,
                    const float* __restrict__ ad_, int2* __restrict__ sw, int etot) {
    int j = blockIdx.x * BS + threadIdx.x;
    if (j >= etot) return;
    int2 p = sn[j];
    float t = as_[p.x >> 8] + ad_[p.y];
    t = t > 0.f ? t : NEG_SLOPE * t;
    float w = __expf(fminf(t, 70.f));
    sw[j] = make_int2(p.x, __float_as_int(w));
}

// ============================ fp16 staging (merged) ============================
// blocks [0, xblocks): xb rows; rest: both weight transposes.
__global__ void k_cvt(const float* __restrict__ x, const int* __restrict__ cid,
                      const float* __restrict__ emb, _Float16* __restrict__ xb,
                      const float* __restrict__ W1, const float* __restrict__ W2,
                      _Float16* __restrict__ Wt1, _Float16* __restrict__ Wt2,
                      int n, int npad, int xblocks) {
    if (blockIdx.x < xblocks) {
        int r = blockIdx.x * 8 + (threadIdx.x >> 5);
        int c = threadIdx.x & 31;
        if (r >= npad) return;
        _Float16* row = xb + (size_t)r * 160;
        if (r < n) {
            const float* xr = x + (size_t)r * 128;
            #pragma unroll
            for (int k = 0; k < 4; ++k) row[c + 32 * k] = (_Float16)xr[c + 32 * k];
            float v = (c < 8) ? emb[cid[r] * 8 + c] : 0.f;
            row[128 + c] = (_Float16)v;
        } else {
            #pragma unroll
            for (int k = 0; k < 5; ++k) row[c + 32 * k] = (_Float16)0.f;
        }
    } else {
        int idx = (blockIdx.x - xblocks) * BS + threadIdx.x;
        if (idx < 128 * 160) {
            int nn = idx / 160, k = idx - nn * 160;
            Wt1[idx] = (_Float16)((k < 136) ? W1[(size_t)k * 128 + nn] : 0.f);
        } else if (idx < 128 * 160 + 128 * 128) {
            int j = idx - 128 * 160;
            int nn = j >> 7, k = j & 127;
            Wt2[j] = (_Float16)W2[(size_t)k * 128 + nn];
        }
    }
}

// ============================ MFMA GEMM ============================
// One wave per 64 rows x 128 cols; operand roles swapped so D holds h^T
// fragments (lane owns 4 consecutive cols of one row per (s,t) tile).
template<int KP>
__global__ __launch_bounds__(64) void k_gemm_mfma(
    const _Float16* __restrict__ A, const _Float16* __restrict__ Bt,
    const float* __restrict__ a_src, const float* __restrict__ a_dst,
    _Float16* __restrict__ hb, float* __restrict__ as_,
    float* __restrict__ ad_, int n)
{
    int lane = threadIdx.x;
    int r15 = lane & 15, q = lane >> 4;
    int rowBase = blockIdx.x * 64;

    f32x4 acc[8][4] = {};   // [s: col tile][t: row tile]

    const _Float16* Wp[8];
    #pragma unroll
    for (int s = 0; s < 8; ++s)
        Wp[s] = Bt + (size_t)(s * 16 + r15) * KP + q * 8;
    const _Float16* Xp[4];
    #pragma unroll
    for (int t = 0; t < 4; ++t)
        Xp[t] = A + (size_t)(rowBase + t * 16 + r15) * KP + q * 8;

    #pragma unroll
    for (int k0 = 0; k0 < KP; k0 += 32) {
        f16x8 wv[8], xv[4];
        #pragma unroll
        for (int s = 0; s < 8; ++s) wv[s] = *(const f16x8*)(Wp[s] + k0);
        #pragma unroll
        for (int t = 0; t < 4; ++t) xv[t] = *(const f16x8*)(Xp[t] + k0);
        #pragma unroll
        for (int s = 0; s < 8; ++s)
            #pragma unroll
            for (int t = 0; t < 4; ++t)
                acc[s][t] = __builtin_amdgcn_mfma_f32_16x16x32_f16(wv[s], xv[t], acc[s][t], 0, 0, 0);
    }

    float4 asv[8], adv[8];
    #pragma unroll
    for (int s = 0; s < 8; ++s) {
        asv[s] = *(const float4*)&a_src[s * 16 + q * 4];
        adv[s] = *(const float4*)&a_dst[s * 16 + q * 4];
    }

    #pragma unroll
    for (int t = 0; t < 4; ++t) {
        int row = rowBase + t * 16 + r15;
        bool ok = row < n;
        float vs = 0.f, vd = 0.f;
        #pragma unroll
        for (int s = 0; s < 8; ++s) {
            f32x4 d = acc[s][t];
            vs += d[0]*asv[s].x + d[1]*asv[s].y + d[2]*asv[s].z + d[3]*asv[s].w;
            vd += d[0]*adv[s].x + d[1]*adv[s].y + d[2]*adv[s].z + d[3]*adv[s].w;
            if (ok) {
                ushort4 u;
                u.x = __half_as_ushort(__float2half_rn(d[0]));
                u.y = __half_as_ushort(__float2half_rn(d[1]));
                u.z = __half_as_ushort(__float2half_rn(d[2]));
                u.w = __half_as_ushort(__float2half_rn(d[3]));
                *(ushort4*)&hb[(size_t)row * 128 + s * 16 + q * 4] = u;
            }
        }
        vs += __shfl_xor(vs, 16); vs += __shfl_xor(vs, 32);
        vd += __shfl_xor(vd, 16); vd += __shfl_xor(vd, 32);
        if (ok && q == 0) { as_[row] = vs; ad_[row] = vd; }
    }
}

// ============================ aggregation ============================
// one wave per dst node, quarter-wave layout: lane l4=lane&15 owns channels
// [8*l4, 8*l4+8); quarters process 4 edges per dwordx4 gather. dsum is
// accumulated per-lane (quarter partials) and combined by the same 2
// shfl_xor as the channel accumulators.
template<bool LN_ELU, bool OUT_HALF>
__global__ __launch_bounds__(256) void k_agg(
    const _Float16* __restrict__ hb, const int2* __restrict__ sw,
    const int2* __restrict__ offs2, const float* __restrict__ bias,
    const float* __restrict__ ln_g, const float* __restrict__ ln_b,
    void* __restrict__ outv, int n_nodes)
{
    int wave = threadIdx.x >> 6, lane = threadIdx.x & 63;
    int n = blockIdx.x * 4 + wave;
    if (n >= n_nodes) return;
    int2 se = offs2[n];
    int start = __builtin_amdgcn_readfirstlane(se.x);
    int len   = __builtin_amdgcn_readfirstlane(se.y);
    int l4 = lane & 15, q = lane >> 4;
    const char* hbB = (const char*)hb;

    float acc[8] = {0.f, 0.f, 0.f, 0.f, 0.f, 0.f, 0.f, 0.f};
    float dsum = 0.f;
    for (int j = 0; j < len; j += 16) {
        int rem = len - j;                    // uniform
        int2 p = sw[start + j + l4];          // 16 entries, replicated per quarter
        #pragma unroll
        for (int v = 0; v < 4; ++v) {
            int e = 4 * v + q;                              // this lane's edge
            int offB = __shfl(p.x, e);
            float w  = __shfl(__int_as_float(p.y), e);
            w = (e < rem) ? w : 0.f;                        // OOB slots -> w=0
            f16x8 hv = *(const f16x8*)(hbB + offB + l4 * 16);
            #pragma unroll
            for (int c = 0; c < 8; ++c)
                acc[c] = fmaf(w, (float)hv[c], acc[c]);
            dsum += w;
        }
    }
    // combine the 4 quarters (lanes l4, l4+16, l4+32, l4+48)
    #pragma unroll
    for (int c = 0; c < 8; ++c) {
        acc[c] += __shfl_xor(acc[c], 16);
        acc[c] += __shfl_xor(acc[c], 32);
    }
    dsum += __shfl_xor(dsum, 16);
    dsum += __shfl_xor(dsum, 32);

    float inv = 1.f / dsum;
    float4 b0 = *(const float4*)&bias[l4 * 8];
    float4 b1 = *(const float4*)&bias[l4 * 8 + 4];
    float vv[8];
    vv[0] = acc[0] * inv + b0.x; vv[1] = acc[1] * inv + b0.y;
    vv[2] = acc[2] * inv + b0.z; vv[3] = acc[3] * inv + b0.w;
    vv[4] = acc[4] * inv + b1.x; vv[5] = acc[5] * inv + b1.y;
    vv[6] = acc[6] * inv + b1.z; vv[7] = acc[7] * inv + b1.w;

    if (LN_ELU) {
        float s1 = 0.f, s2 = 0.f;
        #pragma unroll
        for (int c = 0; c < 8; ++c) { s1 += vv[c]; s2 += vv[c] * vv[c]; }
        #pragma unroll
        for (int o = 1; o < 16; o <<= 1) {    // across the 16 l4 lanes
            s1 += __shfl_xor(s1, o);
            s2 += __shfl_xor(s2, o);
        }
        float mean = s1 * (1.f / 128.f);
        float var  = s2 * (1.f / 128.f) - mean * mean;
        float r = rsqrtf(var + LN_EPS);
        float4 g0 = *(const float4*)&ln_g[l4 * 8];
        float4 g1 = *(const float4*)&ln_g[l4 * 8 + 4];
        float4 p0 = *(const float4*)&ln_b[l4 * 8];
        float4 p1 = *(const float4*)&ln_b[l4 * 8 + 4];
        float gg[8] = {g0.x, g0.y, g0.z, g0.w, g1.x, g1.y, g1.z, g1.w};
        float pp[8] = {p0.x, p0.y, p0.z, p0.w, p1.x, p1.y, p1.z, p1.w};
        #pragma unroll
        for (int c = 0; c < 8; ++c) {
            float t = (vv[c] - mean) * r * gg[c] + pp[c];
            vv[c] = t > 0.f ? t : __expf(t) - 1.f;   // ELU
        }
    }

    if (q == 0) {
        if (OUT_HALF) {
            _Float16* out = (_Float16*)outv;
            f16x8 o;
            #pragma unroll
            for (int c = 0; c < 8; ++c) o[c] = (_Float16)vv[c];
            *(f16x8*)(out + (size_t)n * 128 + l4 * 8) = o;
        } else {
            float* out = (float*)outv;
            float4 o0 = make_float4(vv[0], vv[1], vv[2], vv[3]);
            float4 o1 = make_float4(vv[4], vv[5], vv[6], vv[7]);
            *(float4*)(out + (size_t)n * 128 + l4 * 8)     = o0;
            *(float4*)(out + (size_t)n * 128 + l4 * 8 + 4) = o1;
        }
    }
}

// ============================ launch ============================

extern "C" void kernel_launch(void* const* d_in, const int* in_sizes, int n_in,
                              void* d_out, int out_size, void* d_ws, size_t ws_size,
                              hipStream_t stream) {
    const float* x_base   = (const float*)d_in[0];
    const int*   cell_ids = (const int*)d_in[1];
    const int*   eidx     = (const int*)d_in[2];
    const float* cell_emb = (const float*)d_in[3];
    const float* W1     = (const float*)d_in[4];
    const float* a_src1 = (const float*)d_in[5];
    const float* a_dst1 = (const float*)d_in[6];
    const float* b1     = (const float*)d_in[7];
    const float* ln_g   = (const float*)d_in[8];
    const float* ln_b   = (const float*)d_in[9];
    const float* W2     = (const float*)d_in[10];
    const float* a_src2 = (const float*)d_in[11];
    const float* a_dst2 = (const float*)d_in[12];
    const float* b2     = (const float*)d_in[13];

    const int N = in_sizes[0] / 128;
    const int E = in_sizes[2] / 2;
    const int ETOT = E + N;
    const int gridG = (N + 63) / 64;
    const int Npad  = gridG * 64;

    const int* esrc = eidx;
    const int* edst = eidx + E;

    auto align = [](size_t v) { return (v + 255) & ~(size_t)255; };
    char* p = (char*)d_ws;
    int*   head   = (int*)p;   p += align((size_t)N * 4);
    int*   deg    = (int*)p;   p += align((size_t)N * 4);
    int2*  offs2  = (int2*)p;  p += align((size_t)N * 8);
    int*   gctr   = (int*)p;   p += align(256);
    int2*  nxt2   = (int2*)p;  p += align((size_t)ETOT * 8);
    int2*  sn     = (int2*)p;  p += align((size_t)ETOT * 8);
    int2*  sw     = (int2*)p;  p += align((size_t)(ETOT + 16) * 8);
    _Float16* xb  = (_Float16*)p; p += align((size_t)Npad * 160 * 2);
    _Float16* yb  = (_Float16*)p; p += align((size_t)Npad * 128 * 2);
    _Float16* hb  = (_Float16*)p; p += align((size_t)N * 128 * 2);
    _Float16* Wt1 = (_Float16*)p; p += align((size_t)128 * 160 * 2);
    _Float16* Wt2 = (_Float16*)p; p += align((size_t)128 * 128 * 2);
    float* as_    = (float*)p; p += align((size_t)N * 4);
    float* ad_    = (float*)p; p += align((size_t)N * 4);
    (void)ws_size; (void)n_in; (void)out_size;

    const int nbN = (N + BS - 1) / BS;
    const int nbE = (ETOT + BS - 1) / BS;
    const int xblocks = (Npad + 7) / 8;
    const int wblocks = (128 * 160 + 128 * 128 + BS - 1) / BS;

    hipMemsetAsync(head, 0xFF, (size_t)N * 4, stream);   // head = -1
    hipMemsetAsync(deg, 0, (size_t)N * 4, stream);
    k_link<<<nbE, BS, 0, stream>>>(esrc, edst, head, deg, nxt2, gctr, sw, E, ETOT);
    k_slots<<<nbN, BS, 0, stream>>>(head, nxt2, deg, gctr, offs2, sn, N);
    k_cvt<<<xblocks + wblocks, BS, 0, stream>>>(x_base, cell_ids, cell_emb, xb,
                                                W1, W2, Wt1, Wt2, N, Npad, xblocks);

    // ---- layer 1
    k_gemm_mfma<160><<<gridG, 64, 0, stream>>>(xb, Wt1, a_src1, a_dst1, hb, as_, ad_, N);
    k_w<<<nbE, BS, 0, stream>>>(sn, as_, ad_, sw, ETOT);
    k_agg<true, true><<<(N + 3) / 4, 256, 0, stream>>>(
        hb, sw, offs2, b1, ln_g, ln_b, (void*)yb, N);

    // ---- layer 2
    k_gemm_mfma<128><<<gridG, 64, 0, stream>>>(yb, Wt2, a_src2, a_dst2, hb, as_, ad_, N);
    k_w<<<nbE, BS, 0, stream>>>(sn, as_, ad_, sw, ETOT);
    k_agg<false, false><<<(N + 3) / 4, 256, 0, stream>>>(
        hb, sw, offs2, b2, ln_g, ln_b, d_out, N);
}

// Round 10
// 242.806 us; speedup vs baseline: 1.1691x; 1.1691x over previous
//
#include <hip/hip_runtime.h>
#include <hip/hip_fp16.h>
#include <cstdint>
#include <cstddef>

#define NEG_SLOPE 0.2f
#define LN_EPS 1e-5f

constexpr int BS = 256;

typedef _Float16 f16x8 __attribute__((ext_vector_type(8)));
typedef float f32x4 __attribute__((ext_vector_type(4)));

// ==================== fused: linked-list build + fp16 staging ====================
// Blocks [0,nbE): link edges (head[]=-1 via memset; ONE atomicExch per edge —
// the single random atomic; nxt2 write is coalesced).
// Blocks [nbE, nbE+xblocks): xb fp16 staging (x_base | emb | zero pad).
// Remaining blocks: both weight transposes.
__global__ void k_link_cvt(
    const int* __restrict__ esrc, const int* __restrict__ edst,
    int* __restrict__ head, int2* __restrict__ nxt2, int* __restrict__ gctr,
    int* __restrict__ sn,
    const float* __restrict__ x, const int* __restrict__ cid,
    const float* __restrict__ emb, _Float16* __restrict__ xb,
    const float* __restrict__ W1, const float* __restrict__ W2,
    _Float16* __restrict__ Wt1, _Float16* __restrict__ Wt2,
    int e, int etot, int n, int npad, int nbE, int xblocks)
{
    int b = blockIdx.x;
    if (b < nbE) {
        int i = b * BS + threadIdx.x;
        if (i == 0) *gctr = 0;
        if (i < 16) sn[etot + i] = 0;          // pad: OOB-gather safety
        if (i >= etot) return;
        int s, d;
        if (i < e) { s = esrc[i]; d = edst[i]; }
        else       { s = d = i - e; }          // self loop
        int old = atomicExch(&head[d], i);
        nxt2[i] = make_int2(old, s);           // {next ptr, src node}
    } else if (b < nbE + xblocks) {
        int r = (b - nbE) * 8 + (threadIdx.x >> 5);
        int c = threadIdx.x & 31;
        if (r >= npad) return;
        _Float16* row = xb + (size_t)r * 160;
        if (r < n) {
            const float* xr = x + (size_t)r * 128;
            #pragma unroll
            for (int k = 0; k < 4; ++k) row[c + 32 * k] = (_Float16)xr[c + 32 * k];
            float v = (c < 8) ? emb[cid[r] * 8 + c] : 0.f;
            row[128 + c] = (_Float16)v;
        } else {
            #pragma unroll
            for (int k = 0; k < 5; ++k) row[c + 32 * k] = (_Float16)0.f;
        }
    } else {
        int idx = (b - nbE - xblocks) * BS + threadIdx.x;
        if (idx < 128 * 160) {
            int nn = idx / 160, k = idx - nn * 160;
            Wt1[idx] = (_Float16)((k < 136) ? W1[(size_t)k * 128 + nn] : 0.f);
        } else if (idx < 128 * 160 + 128 * 128) {
            int j = idx - 128 * 160;
            int nn = j >> 7, k = j & 127;
            Wt2[j] = (_Float16)W2[(size_t)k * 128 + nn];
        }
    }
}

// ==================== slots: two-walk, block-scanned segment reserve =========
// Walk 1 counts degree (cold); LDS inclusive scan + ONE gctr atomic per block
// (196 total); walk 2 (L1-warm nxt2) writes per-slot src byte-offsets.
__global__ void k_slots(const int* __restrict__ head, const int2* __restrict__ nxt2,
                        int* __restrict__ gctr, int2* __restrict__ offs2,
                        int* __restrict__ sn, int n) {
    __shared__ int sm[BS];
    __shared__ int base;
    int i = blockIdx.x * BS + threadIdx.x;
    int len = 0;
    if (i < n) {
        int j = head[i];
        while (j >= 0) { ++len; j = nxt2[j].x; }
    }
    sm[threadIdx.x] = len;
    __syncthreads();
    for (int o = 1; o < BS; o <<= 1) {
        int t = (threadIdx.x >= o) ? sm[threadIdx.x - o] : 0;
        __syncthreads();
        sm[threadIdx.x] += t;
        __syncthreads();
    }
    if (threadIdx.x == BS - 1) base = atomicAdd(gctr, sm[BS - 1]);
    __syncthreads();
    if (i < n) {
        int pos = base + sm[threadIdx.x] - len;
        offs2[i] = make_int2(pos, len);
        int j = head[i];
        while (j >= 0) {
            int2 p = nxt2[j];
            sn[pos++] = p.y << 8;   // src*256 = fp16 row byte offset
            j = p.x;
        }
    }
}

// ============================ MFMA GEMM ============================
// One wave per 64 rows x 128 cols; operand roles swapped so D holds h^T
// fragments (lane owns 4 consecutive cols of one row per (s,t) tile).
template<int KP>
__global__ __launch_bounds__(64) void k_gemm_mfma(
    const _Float16* __restrict__ A, const _Float16* __restrict__ Bt,
    const float* __restrict__ a_src, const float* __restrict__ a_dst,
    _Float16* __restrict__ hb, float* __restrict__ as_,
    float* __restrict__ ad_, int n)
{
    int lane = threadIdx.x;
    int r15 = lane & 15, q = lane >> 4;
    int rowBase = blockIdx.x * 64;

    f32x4 acc[8][4] = {};   // [s: col tile][t: row tile]

    const _Float16* Wp[8];
    #pragma unroll
    for (int s = 0; s < 8; ++s)
        Wp[s] = Bt + (size_t)(s * 16 + r15) * KP + q * 8;
    const _Float16* Xp[4];
    #pragma unroll
    for (int t = 0; t < 4; ++t)
        Xp[t] = A + (size_t)(rowBase + t * 16 + r15) * KP + q * 8;

    #pragma unroll
    for (int k0 = 0; k0 < KP; k0 += 32) {
        f16x8 wv[8], xv[4];
        #pragma unroll
        for (int s = 0; s < 8; ++s) wv[s] = *(const f16x8*)(Wp[s] + k0);
        #pragma unroll
        for (int t = 0; t < 4; ++t) xv[t] = *(const f16x8*)(Xp[t] + k0);
        #pragma unroll
        for (int s = 0; s < 8; ++s)
            #pragma unroll
            for (int t = 0; t < 4; ++t)
                acc[s][t] = __builtin_amdgcn_mfma_f32_16x16x32_f16(wv[s], xv[t], acc[s][t], 0, 0, 0);
    }

    float4 asv[8], adv[8];
    #pragma unroll
    for (int s = 0; s < 8; ++s) {
        asv[s] = *(const float4*)&a_src[s * 16 + q * 4];
        adv[s] = *(const float4*)&a_dst[s * 16 + q * 4];
    }

    #pragma unroll
    for (int t = 0; t < 4; ++t) {
        int row = rowBase + t * 16 + r15;
        bool ok = row < n;
        float vs = 0.f, vd = 0.f;
        #pragma unroll
        for (int s = 0; s < 8; ++s) {
            f32x4 d = acc[s][t];
            vs += d[0]*asv[s].x + d[1]*asv[s].y + d[2]*asv[s].z + d[3]*asv[s].w;
            vd += d[0]*adv[s].x + d[1]*adv[s].y + d[2]*adv[s].z + d[3]*adv[s].w;
            if (ok) {
                ushort4 u;
                u.x = __half_as_ushort(__float2half_rn(d[0]));
                u.y = __half_as_ushort(__float2half_rn(d[1]));
                u.z = __half_as_ushort(__float2half_rn(d[2]));
                u.w = __half_as_ushort(__float2half_rn(d[3]));
                *(ushort4*)&hb[(size_t)row * 128 + s * 16 + q * 4] = u;
            }
        }
        vs += __shfl_xor(vs, 16); vs += __shfl_xor(vs, 32);
        vd += __shfl_xor(vd, 16); vd += __shfl_xor(vd, 32);
        if (ok && q == 0) { as_[row] = vs; ad_[row] = vd; }
    }
}

// ============================ aggregation (fused w) ============================
// one wave per dst node, quarter-wave layout: lane l4=lane&15 owns channels
// [8*l4, 8*l4+8); quarters process 4 edges per dwordx4 gather. Edge weights
// computed INLINE (16 as_ gathers + exp per 16-edge chunk — hidden under the
// row gathers); no k_w pass, no sw buffer. dsum per-lane, combined by the
// same 2 shfl_xor as the channel accumulators.
template<bool LN_ELU, bool OUT_HALF>
__global__ __launch_bounds__(256) void k_agg(
    const _Float16* __restrict__ hb, const int* __restrict__ sn,
    const int2* __restrict__ offs2, const float* __restrict__ as_,
    const float* __restrict__ ad_, const float* __restrict__ bias,
    const float* __restrict__ ln_g, const float* __restrict__ ln_b,
    void* __restrict__ outv, int n_nodes)
{
    int wave = threadIdx.x >> 6, lane = threadIdx.x & 63;
    int n = blockIdx.x * 4 + wave;
    if (n >= n_nodes) return;
    int2 se = offs2[n];
    int start = __builtin_amdgcn_readfirstlane(se.x);
    int len   = __builtin_amdgcn_readfirstlane(se.y);
    int l4 = lane & 15, q = lane >> 4;
    float adv = ad_[n];
    const char* hbB = (const char*)hb;

    float acc[8] = {0.f, 0.f, 0.f, 0.f, 0.f, 0.f, 0.f, 0.f};
    float dsum = 0.f;
    for (int j = 0; j < len; j += 16) {
        int rem = len - j;                      // uniform
        int offB = sn[start + j + l4];          // 16 entries, replicated x4
        float t = as_[offB >> 8] + adv;         // inline weight
        t = t > 0.f ? t : NEG_SLOPE * t;
        float w0 = __expf(fminf(t, 70.f));
        #pragma unroll
        for (int v = 0; v < 4; ++v) {
            int e = 4 * v + q;                  // this lane's edge
            int ob  = __shfl(offB, e);
            float w = __shfl(w0, e);
            w = (e < rem) ? w : 0.f;            // OOB slots -> w=0
            f16x8 hv = *(const f16x8*)(hbB + ob + l4 * 16);
            #pragma unroll
            for (int c = 0; c < 8; ++c)
                acc[c] = fmaf(w, (float)hv[c], acc[c]);
            dsum += w;
        }
    }
    // combine the 4 quarters (lanes l4, l4+16, l4+32, l4+48)
    #pragma unroll
    for (int c = 0; c < 8; ++c) {
        acc[c] += __shfl_xor(acc[c], 16);
        acc[c] += __shfl_xor(acc[c], 32);
    }
    dsum += __shfl_xor(dsum, 16);
    dsum += __shfl_xor(dsum, 32);

    float inv = 1.f / dsum;
    float4 b0 = *(const float4*)&bias[l4 * 8];
    float4 b1 = *(const float4*)&bias[l4 * 8 + 4];
    float vv[8];
    vv[0] = acc[0] * inv + b0.x; vv[1] = acc[1] * inv + b0.y;
    vv[2] = acc[2] * inv + b0.z; vv[3] = acc[3] * inv + b0.w;
    vv[4] = acc[4] * inv + b1.x; vv[5] = acc[5] * inv + b1.y;
    vv[6] = acc[6] * inv + b1.z; vv[7] = acc[7] * inv + b1.w;

    if (LN_ELU) {
        float s1 = 0.f, s2 = 0.f;
        #pragma unroll
        for (int c = 0; c < 8; ++c) { s1 += vv[c]; s2 += vv[c] * vv[c]; }
        #pragma unroll
        for (int o = 1; o < 16; o <<= 1) {    // across the 16 l4 lanes
            s1 += __shfl_xor(s1, o);
            s2 += __shfl_xor(s2, o);
        }
        float mean = s1 * (1.f / 128.f);
        float var  = s2 * (1.f / 128.f) - mean * mean;
        float r = rsqrtf(var + LN_EPS);
        float4 g0 = *(const float4*)&ln_g[l4 * 8];
        float4 g1 = *(const float4*)&ln_g[l4 * 8 + 4];
        float4 p0 = *(const float4*)&ln_b[l4 * 8];
        float4 p1 = *(const float4*)&ln_b[l4 * 8 + 4];
        float gg[8] = {g0.x, g0.y, g0.z, g0.w, g1.x, g1.y, g1.z, g1.w};
        float pp[8] = {p0.x, p0.y, p0.z, p0.w, p1.x, p1.y, p1.z, p1.w};
        #pragma unroll
        for (int c = 0; c < 8; ++c) {
            float t = (vv[c] - mean) * r * gg[c] + pp[c];
            vv[c] = t > 0.f ? t : __expf(t) - 1.f;   // ELU
        }
    }

    if (q == 0) {
        if (OUT_HALF) {
            _Float16* out = (_Float16*)outv;
            f16x8 o;
            #pragma unroll
            for (int c = 0; c < 8; ++c) o[c] = (_Float16)vv[c];
            *(f16x8*)(out + (size_t)n * 128 + l4 * 8) = o;
        } else {
            float* out = (float*)outv;
            float4 o0 = make_float4(vv[0], vv[1], vv[2], vv[3]);
            float4 o1 = make_float4(vv[4], vv[5], vv[6], vv[7]);
            *(float4*)(out + (size_t)n * 128 + l4 * 8)     = o0;
            *(float4*)(out + (size_t)n * 128 + l4 * 8 + 4) = o1;
        }
    }
}

// ============================ launch ============================

extern "C" void kernel_launch(void* const* d_in, const int* in_sizes, int n_in,
                              void* d_out, int out_size, void* d_ws, size_t ws_size,
                              hipStream_t stream) {
    const float* x_base   = (const float*)d_in[0];
    const int*   cell_ids = (const int*)d_in[1];
    const int*   eidx     = (const int*)d_in[2];
    const float* cell_emb = (const float*)d_in[3];
    const float* W1     = (const float*)d_in[4];
    const float* a_src1 = (const float*)d_in[5];
    const float* a_dst1 = (const float*)d_in[6];
    const float* b1     = (const float*)d_in[7];
    const float* ln_g   = (const float*)d_in[8];
    const float* ln_b   = (const float*)d_in[9];
    const float* W2     = (const float*)d_in[10];
    const float* a_src2 = (const float*)d_in[11];
    const float* a_dst2 = (const float*)d_in[12];
    const float* b2     = (const float*)d_in[13];

    const int N = in_sizes[0] / 128;
    const int E = in_sizes[2] / 2;
    const int ETOT = E + N;
    const int gridG = (N + 63) / 64;
    const int Npad  = gridG * 64;

    const int* esrc = eidx;
    const int* edst = eidx + E;

    auto align = [](size_t v) { return (v + 255) & ~(size_t)255; };
    char* p = (char*)d_ws;
    int*   head   = (int*)p;   p += align((size_t)N * 4);
    int2*  offs2  = (int2*)p;  p += align((size_t)N * 8);
    int*   gctr   = (int*)p;   p += align(256);
    int2*  nxt2   = (int2*)p;  p += align((size_t)ETOT * 8);
    int*   sn     = (int*)p;   p += align((size_t)(ETOT + 16) * 4);
    _Float16* xb  = (_Float16*)p; p += align((size_t)Npad * 160 * 2);
    _Float16* yb  = (_Float16*)p; p += align((size_t)Npad * 128 * 2);
    _Float16* hb  = (_Float16*)p; p += align((size_t)N * 128 * 2);
    _Float16* Wt1 = (_Float16*)p; p += align((size_t)128 * 160 * 2);
    _Float16* Wt2 = (_Float16*)p; p += align((size_t)128 * 128 * 2);
    float* as_    = (float*)p; p += align((size_t)N * 4);
    float* ad_    = (float*)p; p += align((size_t)N * 4);
    (void)ws_size; (void)n_in; (void)out_size;

    const int nbN = (N + BS - 1) / BS;
    const int nbE = (ETOT + BS - 1) / BS;
    const int xblocks = (Npad + 7) / 8;
    const int wblocks = (128 * 160 + 128 * 128 + BS - 1) / BS;

    hipMemsetAsync(head, 0xFF, (size_t)N * 4, stream);   // head = -1
    k_link_cvt<<<nbE + xblocks + wblocks, BS, 0, stream>>>(
        esrc, edst, head, nxt2, gctr, sn,
        x_base, cell_ids, cell_emb, xb, W1, W2, Wt1, Wt2,
        E, ETOT, N, Npad, nbE, xblocks);
    k_slots<<<nbN, BS, 0, stream>>>(head, nxt2, gctr, offs2, sn, N);

    // ---- layer 1
    k_gemm_mfma<160><<<gridG, 64, 0, stream>>>(xb, Wt1, a_src1, a_dst1, hb, as_, ad_, N);
    k_agg<true, true><<<(N + 3) / 4, 256, 0, stream>>>(
        hb, sn, offs2, as_, ad_, b1, ln_g, ln_b, (void*)yb, N);

    // ---- layer 2
    k_gemm_mfma<128><<<gridG, 64, 0, stream>>>(yb, Wt2, a_src2, a_dst2, hb, as_, ad_, N);
    k_agg<false, false><<<(N + 3) / 4, 256, 0, stream>>>(
        hb, sn, offs2, as_, ad_, b2, ln_g, ln_b, d_out, N);
}